// Round 7
// baseline (356.081 us; speedup 1.0000x reference)
//
#include <hip/hip_runtime.h>

#define NROW 8192
#define INF  512
#define OUTF 256
#define M_ELEM (NROW * OUTF)   // 2,097,152 f32 per output matrix

typedef __bf16 v8bf __attribute__((ext_vector_type(8)));
typedef __bf16 v4bf __attribute__((ext_vector_type(4)));
typedef float  v4f  __attribute__((ext_vector_type(4)));

__device__ __forceinline__ v8bf cvt_bf8(v4f u0, v4f u1) {
  v8bf v;
  v[0]=(__bf16)u0[0]; v[1]=(__bf16)u0[1]; v[2]=(__bf16)u0[2]; v[3]=(__bf16)u0[3];
  v[4]=(__bf16)u1[0]; v[5]=(__bf16)u1[1]; v[6]=(__bf16)u1[2]; v[7]=(__bf16)u1[3];
  return v;
}

// ---------------------------------------------------------------------------
// Kernel A: seq = feat @ W^T, bf16 MFMA, output in B-fragment-packed layout:
//   elem(m,o) -> (((m>>5)*16 + (o>>4))*64 + ((m>>3)&3)*16 + (o&15))*8 + (m&7)
// ---------------------------------------------------------------------------
__global__ __launch_bounds__(256) void seq_fts_kernel(
    const float* __restrict__ feat, const float* __restrict__ W,
    __bf16* __restrict__ Bp) {
  const int tid  = threadIdx.x;
  const int lane = tid & 63, w = tid >> 6;
  const int llo  = lane & 15, lhi = lane >> 4;
  const int row0 = blockIdx.x * 64;
  const int col0 = w * 64;

  v4f acc[4][4] = {};
#pragma unroll 1
  for (int kb = 0; kb < INF / 32; ++kb) {
    const int kofs = kb * 32 + lhi * 8;
    v8bf a[4], b[4];
#pragma unroll
    for (int i = 0; i < 4; ++i) {
      const float* p = feat + (size_t)(row0 + i * 16 + llo) * INF + kofs;
      a[i] = cvt_bf8(*(const v4f*)p, *(const v4f*)(p + 4));
    }
#pragma unroll
    for (int i = 0; i < 4; ++i) {
      const float* p = W + (size_t)(col0 + i * 16 + llo) * INF + kofs;
      b[i] = cvt_bf8(*(const v4f*)p, *(const v4f*)(p + 4));
    }
#pragma unroll
    for (int ri = 0; ri < 4; ++ri)
#pragma unroll
      for (int ci = 0; ci < 4; ++ci)
        acc[ri][ci] = __builtin_amdgcn_mfma_f32_16x16x32_bf16(
            a[ri], b[ci], acc[ri][ci], 0, 0, 0);
  }
#pragma unroll
  for (int ri = 0; ri < 4; ++ri)
#pragma unroll
    for (int ci = 0; ci < 4; ++ci) {
      const int mf = row0 + ri * 16 + lhi * 4;
      const int o  = col0 + ci * 16 + llo;
      size_t e = (((size_t)(mf >> 5) * 16 + (o >> 4)) * 64 +
                  ((mf >> 3) & 3) * 16 + (o & 15)) * 8 + (mf & 7);
      v4bf v;
      v[0] = (__bf16)acc[ri][ci][0]; v[1] = (__bf16)acc[ri][ci][1];
      v[2] = (__bf16)acc[ri][ci][2]; v[3] = (__bf16)acc[ri][ci][3];
      *(v4bf*)(Bp + e) = v;
    }
}

// ---------------------------------------------------------------------------
// Kernel B: out = prelu(adj @ seq + bias).
// PURE DATAFLOW: no LDS, no barriers, no manual waitcnt. Block = 4 waves;
// wave w owns rows [row0,row0+64) x cols [w*64,(w+1)*64). A-fragments loaded
// directly from adj in MFMA fragment order (row=llo, k=lhi*8), TRIPLE-buffered
// (prefetch distance 2 micro-steps covers HBM latency); B-fragments are single
// dwordx4 loads from the packed, L2-hot Bp. The 4 col-waves read the same A
// rows ~in step -> followers hit L1/L2, adj HBM traffic stays ~1x.
// Compiler inserts precise counted vmcnt for every reg load.
// ---------------------------------------------------------------------------
__global__ __launch_bounds__(256, 1) void gcn_agg_kernel(
    const float* __restrict__ adjA, const float* __restrict__ adjB,
    const __bf16* __restrict__ Bp, const float* __restrict__ bias,
    const float* __restrict__ prelu_a, float* __restrict__ out) {
  const int tid  = threadIdx.x;
  const int lane = tid & 63, w = tid >> 6;
  const int llo  = lane & 15, lhi = lane >> 4;
  const int row0 = blockIdx.x * 64;
  const int z    = blockIdx.y;
  const float* __restrict__ adj = z ? adjB : adjA;

  v4f acc[4][4] = {};   // [rowtile][coltile]

  const float*  abase = adj + (size_t)(row0 + llo) * NROW + lhi * 8;
  const __bf16* bbase = Bp + ((size_t)(w * 4) * 64 + lane) * 8;

  // one micro-step = k-chunk of 32
  auto load_a = [&](int kk, v4f (&a)[8]) {
#pragma unroll
    for (int rt = 0; rt < 4; ++rt) {
      const float* p = abase + (size_t)rt * 16 * NROW + kk * 32;
      a[rt * 2 + 0] = *(const v4f*)p;
      a[rt * 2 + 1] = *(const v4f*)(p + 4);
    }
  };
  auto load_b = [&](int kk, v8bf (&b)[4]) {
#pragma unroll
    for (int ct = 0; ct < 4; ++ct)
      b[ct] = *(const v8bf*)(bbase + ((size_t)kk * 16 + ct) * 512);
  };
  auto compute = [&](v4f (&a)[8], v8bf (&b)[4]) {
#pragma unroll
    for (int rt = 0; rt < 4; ++rt) {
      v8bf av = cvt_bf8(a[rt * 2], a[rt * 2 + 1]);
#pragma unroll
      for (int ct = 0; ct < 4; ++ct)
        acc[rt][ct] = __builtin_amdgcn_mfma_f32_16x16x32_bf16(
            av, b[ct], acc[rt][ct], 0, 0, 0);
    }
  };

  v4f  a0[8], a1[8], a2[8];
  v8bf b0[4], b1[4], b2[4];
  load_a(0, a0); load_b(0, b0);
  load_a(1, a1); load_b(1, b1);

  // 255 = 3*85 micro-steps in the rotated loop; micro 255 handled after.
#pragma unroll 1
  for (int kk = 0; kk < 255; kk += 3) {
    load_a(kk + 2, a2); load_b(kk + 2, b2);
    compute(a0, b0);                               // micro kk
    load_a(kk + 3, a0); load_b(kk + 3, b0);        // kk+3 <= 255
    compute(a1, b1);                               // micro kk+1
    const int k4 = (kk + 4 < 256) ? kk + 4 : 255;  // dup-load, never computed
    load_a(k4, a1); load_b(k4, b1);
    compute(a2, b2);                               // micro kk+2
  }
  compute(a0, b0);                                 // micro 255

  // epilogue: bias + prelu, direct store
  const float slope = prelu_a[0];
  float* __restrict__ outp = out + (size_t)z * M_ELEM;
#pragma unroll
  for (int ct = 0; ct < 4; ++ct) {
    const int o  = w * 64 + ct * 16 + llo;
    const float bs = bias[o];
#pragma unroll
    for (int rt = 0; rt < 4; ++rt) {
      const int m = row0 + rt * 16 + lhi * 4;
#pragma unroll
      for (int r = 0; r < 4; ++r) {
        float v = acc[rt][ct][r] + bs;
        outp[(size_t)(m + r) * OUTF + o] = v >= 0.f ? v : slope * v;
      }
    }
  }
}

extern "C" void kernel_launch(void* const* d_in, const int* in_sizes, int n_in,
                              void* d_out, int out_size, void* d_ws, size_t ws_size,
                              hipStream_t stream) {
  const float* feat = (const float*)d_in[0];
  const float* adj  = (const float*)d_in[1];
  const float* aug  = (const float*)d_in[2];
  const float* W    = (const float*)d_in[3];
  const float* bias = (const float*)d_in[4];
  const float* pa   = (const float*)d_in[5];
  float* out = (float*)d_out;
  __bf16* Bp = (__bf16*)d_ws;                    // 4 MB packed seq_fts

  seq_fts_kernel<<<dim3(NROW / 64), 256, 0, stream>>>(feat, W, Bp);
  gcn_agg_kernel<<<dim3(NROW / 64, 2), 256, 0, stream>>>(
      adj, aug, Bp, bias, pa, out);
}

// Round 8
// 244.457 us; speedup vs baseline: 1.4566x; 1.4566x over previous
//
#include <hip/hip_runtime.h>

#define NROW 8192
#define INF  512
#define OUTF 256
#define M_ELEM (NROW * OUTF)   // 2,097,152 f32 per output matrix

typedef __bf16 v8bf __attribute__((ext_vector_type(8)));
typedef __bf16 v4bf __attribute__((ext_vector_type(4)));
typedef float  v4f  __attribute__((ext_vector_type(4)));

__device__ __forceinline__ v8bf cvt_bf8(v4f u0, v4f u1) {
  v8bf v;
  v[0]=(__bf16)u0[0]; v[1]=(__bf16)u0[1]; v[2]=(__bf16)u0[2]; v[3]=(__bf16)u0[3];
  v[4]=(__bf16)u1[0]; v[5]=(__bf16)u1[1]; v[6]=(__bf16)u1[2]; v[7]=(__bf16)u1[3];
  return v;
}

// ---------------------------------------------------------------------------
// Kernel A: seq = feat @ W^T, bf16 MFMA, output in B-fragment-packed layout:
//   elem(m,o) -> (((m>>5)*16 + (o>>4))*64 + ((m>>3)&3)*16 + (o&15))*8 + (m&7)
// = per (kk=m>>5) a 16 KB chunk of 16 cig x 1 KB, lane-contiguous inside.
// ---------------------------------------------------------------------------
__global__ __launch_bounds__(256) void seq_fts_kernel(
    const float* __restrict__ feat, const float* __restrict__ W,
    __bf16* __restrict__ Bp) {
  const int tid  = threadIdx.x;
  const int lane = tid & 63, w = tid >> 6;
  const int llo  = lane & 15, lhi = lane >> 4;
  const int row0 = blockIdx.x * 64;
  const int col0 = w * 64;

  v4f acc[4][4] = {};
#pragma unroll 1
  for (int kb = 0; kb < INF / 32; ++kb) {
    const int kofs = kb * 32 + lhi * 8;
    v8bf a[4], b[4];
#pragma unroll
    for (int i = 0; i < 4; ++i) {
      const float* p = feat + (size_t)(row0 + i * 16 + llo) * INF + kofs;
      a[i] = cvt_bf8(*(const v4f*)p, *(const v4f*)(p + 4));
    }
#pragma unroll
    for (int i = 0; i < 4; ++i) {
      const float* p = W + (size_t)(col0 + i * 16 + llo) * INF + kofs;
      b[i] = cvt_bf8(*(const v4f*)p, *(const v4f*)(p + 4));
    }
#pragma unroll
    for (int ri = 0; ri < 4; ++ri)
#pragma unroll
      for (int ci = 0; ci < 4; ++ci)
        acc[ri][ci] = __builtin_amdgcn_mfma_f32_16x16x32_bf16(
            a[ri], b[ci], acc[ri][ci], 0, 0, 0);
  }
#pragma unroll
  for (int ri = 0; ri < 4; ++ri)
#pragma unroll
    for (int ci = 0; ci < 4; ++ci) {
      const int mf = row0 + ri * 16 + lhi * 4;
      const int o  = col0 + ci * 16 + llo;
      size_t e = (((size_t)(mf >> 5) * 16 + (o >> 4)) * 64 +
                  ((mf >> 3) & 3) * 16 + (o & 15)) * 8 + (mf & 7);
      v4bf v;
      v[0] = (__bf16)acc[ri][ci][0]; v[1] = (__bf16)acc[ri][ci][1];
      v[2] = (__bf16)acc[ri][ci][2]; v[3] = (__bf16)acc[ri][ci][3];
      *(v4bf*)(Bp + e) = v;
    }
}

// ---------------------------------------------------------------------------
// Kernel B: partial[z,y] = adj_z[128 rows, K-half] @ seq.
// DEEP DMA PIPELINE: A (128x32 f32, 16 KB) AND B (32k x 256 bf16 packed,
// 16 KB) both staged via global_load_lds into D=4 buffers (128 KB LDS).
// Uniform FIFO: 4 instr/wave/step. One counted vmcnt(8) + one raw s_barrier
// per step -> 2 full stages (64 KB/CU) in flight at ALL times; in-flight
// depth lives in the DMA queue, costs zero VGPRs (no pipeline collapse).
// A XOR-swizzled via pre-swizzled SOURCE slot (m173): LDS row r slot p holds
// source k4 = p ^ (r&7); frag read XORs the same -> conflict-free.
// ---------------------------------------------------------------------------
__global__ __launch_bounds__(512, 2) void gcn_agg_kernel(
    const float* __restrict__ adjA, const float* __restrict__ adjB,
    const __bf16* __restrict__ Bp, float* __restrict__ P,
    int S, int nsteps) {
  const int tid  = threadIdx.x;
  const int lane = tid & 63, w = tid >> 6;
  const int llo  = lane & 15, lhi = lane >> 4;
  const int wr   = w >> 1, wc = w & 1;         // 4 row-groups x 2 col-halves
  const int row0 = blockIdx.x * 128;
  const int y    = blockIdx.y;                 // K-slice
  const int z    = blockIdx.z;
  const float* __restrict__ adj = z ? adjB : adjA;
  const int k0     = y * nsteps * 32;          // element-k offset
  const int kkbase = y * nsteps;               // 32-k chunk base

  __shared__ __align__(16) char LdsA[4][16384];
  __shared__ __align__(16) char LdsB[4][16384];

  v4f acc[2][8] = {};

  const int gi0 = w * 2;
  const int rA0 = (lane >> 3);                 // sub-row within A-instr
  const int s4l = (lane & 7);                  // physical slot within row

  auto stage = [&](int buf, int t) {
#pragma unroll
    for (int i = 0; i < 2; ++i) {              // A: 2 instr/wave
      const int gi = gi0 + i;
      const int r  = gi * 8 + rA0;             // tile row 0..127
      const int s4 = s4l ^ (r & 7);            // pre-swizzled source slot
      const float* srcA =
          adj + (size_t)(row0 + r) * NROW + k0 + t * 32 + s4 * 4;
      __builtin_amdgcn_global_load_lds(
          (const __attribute__((address_space(1))) void*)srcA,
          (__attribute__((address_space(3))) void*)(&LdsA[buf][gi * 1024]),
          16, 0, 0);
    }
#pragma unroll
    for (int i = 0; i < 2; ++i) {              // B: 2 instr/wave
      const int gi = gi0 + i;
      const char* srcB = (const char*)Bp +
          ((size_t)(kkbase + t) * 16384 + gi * 1024 + lane * 16);
      __builtin_amdgcn_global_load_lds(
          (const __attribute__((address_space(1))) void*)srcB,
          (__attribute__((address_space(3))) void*)(&LdsB[buf][gi * 1024]),
          16, 0, 0);
    }
  };

  auto compute = [&](int buf) {
    v8bf af[2], bf[8];
    const char* ab = &LdsA[buf][0];
#pragma unroll
    for (int rt = 0; rt < 2; ++rt) {
      const int r = wr * 32 + rt * 16 + llo;
      v4f u0 = *(const v4f*)(ab + r * 128 + (((lhi * 2    ) ^ (r & 7)) << 4));
      v4f u1 = *(const v4f*)(ab + r * 128 + (((lhi * 2 + 1) ^ (r & 7)) << 4));
      af[rt] = cvt_bf8(u0, u1);
    }
    const char* bb = &LdsB[buf][0];
#pragma unroll
    for (int ci = 0; ci < 8; ++ci)
      bf[ci] = *(const v8bf*)(bb + (wc * 8 + ci) * 1024 + lane * 16);
#pragma unroll
    for (int ci = 0; ci < 8; ++ci)
#pragma unroll
      for (int rt = 0; rt < 2; ++rt)
        acc[rt][ci] = __builtin_amdgcn_mfma_f32_16x16x32_bf16(
            af[rt], bf[ci], acc[rt][ci], 0, 0, 0);
  };

  stage(0, 0); stage(1, 1); stage(2, 2);       // 12 instr/wave outstanding

#pragma unroll 1
  for (int t = 0; t < nsteps - 2; ++t) {
    asm volatile("s_waitcnt vmcnt(8)" ::: "memory");   // stage t landed
    __builtin_amdgcn_s_barrier();
    __builtin_amdgcn_sched_barrier(0);
    if (t + 3 < nsteps) stage((t + 3) & 3, t + 3);     // into buf freed at t-1
    __builtin_amdgcn_sched_barrier(0);
    compute(t & 3);
  }
  asm volatile("s_waitcnt vmcnt(4)" ::: "memory");
  __builtin_amdgcn_s_barrier();
  compute((nsteps - 2) & 3);
  asm volatile("s_waitcnt vmcnt(0)" ::: "memory");
  __builtin_amdgcn_s_barrier();
  compute((nsteps - 1) & 3);

  // raw partial sums (bias/prelu in the reduce epilogue)
  float* __restrict__ Pp = P + (size_t)(z * S + y) * M_ELEM;
#pragma unroll
  for (int ci = 0; ci < 8; ++ci) {
    const int o = wc * 128 + ci * 16 + llo;
#pragma unroll
    for (int rt = 0; rt < 2; ++rt) {
      const int m = row0 + wr * 32 + rt * 16 + lhi * 4;
#pragma unroll
      for (int r = 0; r < 4; ++r)
        Pp[(size_t)(m + r) * OUTF + o] = acc[rt][ci][r];
    }
  }
}

// ---------------------------------------------------------------------------
// Epilogue: out = prelu(sum_y partial[z,y] + bias). v4f, grid-stride.
// For S==1, P == out (in-place bias+prelu).
// ---------------------------------------------------------------------------
__global__ __launch_bounds__(256) void reduce_kernel(
    const float* __restrict__ P, const float* __restrict__ bias,
    const float* __restrict__ prelu_a, float* __restrict__ out, int S) {
  const float slope = prelu_a[0];
  const int nv4 = 2 * M_ELEM / 4;
  for (int v = blockIdx.x * 256 + threadIdx.x; v < nv4; v += gridDim.x * 256) {
    const int z = v >> 19;                       // 524288 v4 per matrix
    const size_t r = (size_t)(v & 524287) * 4;
    const int o = (int)(r & 255);
    v4f s = {};
    for (int yy = 0; yy < S; ++yy)
      s += *(const v4f*)(P + (size_t)(z * S + yy) * M_ELEM + r);
    v4f b4 = *(const v4f*)(bias + o);
    s += b4;
    v4f res;
#pragma unroll
    for (int i = 0; i < 4; ++i) res[i] = s[i] >= 0.f ? s[i] : slope * s[i];
    *(v4f*)(out + (size_t)z * M_ELEM + r) = res;
  }
}

extern "C" void kernel_launch(void* const* d_in, const int* in_sizes, int n_in,
                              void* d_out, int out_size, void* d_ws, size_t ws_size,
                              hipStream_t stream) {
  const float* feat = (const float*)d_in[0];
  const float* adj  = (const float*)d_in[1];
  const float* aug  = (const float*)d_in[2];
  const float* W    = (const float*)d_in[3];
  const float* bias = (const float*)d_in[4];
  const float* pa   = (const float*)d_in[5];
  float* out = (float*)d_out;
  __bf16* Bp = (__bf16*)d_ws;                    // 4 MB packed seq_fts

  const size_t MB = 1ull << 20;
  int S = (ws_size >= 4 * MB + 2 * 2 * (size_t)M_ELEM * 4) ? 2 : 1;  // 36 MB
  float* P = (S == 1) ? out : (float*)((char*)d_ws + 4 * MB);
  const int nsteps = NROW / 32 / S;              // 128 (S=2) or 256 (S=1)

  seq_fts_kernel<<<dim3(NROW / 64), 256, 0, stream>>>(feat, W, Bp);
  gcn_agg_kernel<<<dim3(NROW / 128, S, 2), 512, 0, stream>>>(
      adj, aug, Bp, P, S, nsteps);
  reduce_kernel<<<dim3(1024), 256, 0, stream>>>(P, bias, pa, out, S);
}

// Round 9
// 207.938 us; speedup vs baseline: 1.7124x; 1.1756x over previous
//
#include <hip/hip_runtime.h>

#define NROW 8192
#define INF  512
#define OUTF 256
#define M_ELEM (NROW * OUTF)   // 2,097,152 f32 per output matrix
#define NSTEP 32               // K-steps of 256

typedef __bf16 v8bf __attribute__((ext_vector_type(8)));
typedef __bf16 v4bf __attribute__((ext_vector_type(4)));
typedef float  v4f  __attribute__((ext_vector_type(4)));

__device__ __forceinline__ v8bf cvt_bf8(v4f u0, v4f u1) {
  v8bf v;
  v[0]=(__bf16)u0[0]; v[1]=(__bf16)u0[1]; v[2]=(__bf16)u0[2]; v[3]=(__bf16)u0[3];
  v[4]=(__bf16)u1[0]; v[5]=(__bf16)u1[1]; v[6]=(__bf16)u1[2]; v[7]=(__bf16)u1[3];
  return v;
}

// ---------------------------------------------------------------------------
// Kernel A: seq = feat @ W^T, bf16 MFMA, output in B-fragment-packed layout:
//   elem(m,o) -> (((m>>5)*16 + (o>>4))*64 + ((m>>3)&3)*16 + (o&15))*8 + (m&7)
// ---------------------------------------------------------------------------
__global__ __launch_bounds__(256) void seq_fts_kernel(
    const float* __restrict__ feat, const float* __restrict__ W,
    __bf16* __restrict__ Bp) {
  const int tid  = threadIdx.x;
  const int lane = tid & 63, w = tid >> 6;
  const int llo  = lane & 15, lhi = lane >> 4;
  const int row0 = blockIdx.x * 64;
  const int col0 = w * 64;

  v4f acc[4][4] = {};
#pragma unroll 1
  for (int kb = 0; kb < INF / 32; ++kb) {
    const int kofs = kb * 32 + lhi * 8;
    v8bf a[4], b[4];
#pragma unroll
    for (int i = 0; i < 4; ++i) {
      const float* p = feat + (size_t)(row0 + i * 16 + llo) * INF + kofs;
      a[i] = cvt_bf8(*(const v4f*)p, *(const v4f*)(p + 4));
    }
#pragma unroll
    for (int i = 0; i < 4; ++i) {
      const float* p = W + (size_t)(col0 + i * 16 + llo) * INF + kofs;
      b[i] = cvt_bf8(*(const v4f*)p, *(const v4f*)(p + 4));
    }
#pragma unroll
    for (int ri = 0; ri < 4; ++ri)
#pragma unroll
      for (int ci = 0; ci < 4; ++ci)
        acc[ri][ci] = __builtin_amdgcn_mfma_f32_16x16x32_bf16(
            a[ri], b[ci], acc[ri][ci], 0, 0, 0);
  }
#pragma unroll
  for (int ri = 0; ri < 4; ++ri)
#pragma unroll
    for (int ci = 0; ci < 4; ++ci) {
      const int mf = row0 + ri * 16 + lhi * 4;
      const int o  = col0 + ci * 16 + llo;
      size_t e = (((size_t)(mf >> 5) * 16 + (o >> 4)) * 64 +
                  ((mf >> 3) & 3) * 16 + (o & 15)) * 8 + (mf & 7);
      v4bf v;
      v[0] = (__bf16)acc[ri][ci][0]; v[1] = (__bf16)acc[ri][ci][1];
      v[2] = (__bf16)acc[ri][ci][2]; v[3] = (__bf16)acc[ri][ci][3];
      *(v4bf*)(Bp + e) = v;
    }
}

// ---------------------------------------------------------------------------
// Kernel B: out = prelu(adj @ seq + bias).
// HBM-LOCALITY design: per K-step each adj row is read as ONE CONTIGUOUS 1 KB
// burst (one global_load_lds instr/row, NT-hinted: adj never allocates in
// L2/LLC, keeping them for Bp). A-tile 64x256 f32, D=2 LDS (128 KB), XOR-
// swizzled via pre-swizzled source slots. B-frags live in registers (fully
// unrolled, static), issued at top-of-step BEFORE the A-stage so compiler
// B-waits (in-order FIFO) can never force the A prefetch to drain.
// One vmcnt(0)+barrier per step; only A(t)'s 8 loads outstanding there,
// issued a full compute-phase earlier.
// ---------------------------------------------------------------------------
__global__ __launch_bounds__(512, 2) void gcn_agg_kernel(
    const float* __restrict__ adjA, const float* __restrict__ adjB,
    const __bf16* __restrict__ Bp, const float* __restrict__ bias,
    const float* __restrict__ prelu_a, float* __restrict__ out) {
  const int tid  = threadIdx.x;
  const int lane = tid & 63, w = tid >> 6;
  const int llo  = lane & 15, lhi = lane >> 4;
  const int wr   = w >> 2, wc = w & 3;     // 2 row-groups x 4 col-groups
  const int row0 = blockIdx.x * 64;
  const int z    = blockIdx.y;
  const float* __restrict__ adj = z ? adjB : adjA;

  __shared__ __align__(16) char LdsA[2][65536];   // 2 x (64 rows x 1 KB)

  v4f acc[2][4] = {};

  // --- A staging: 8 instr/wave, each = one row's 1 KB contiguous chunk.
  // LDS row r slot p (16B units) holds source slot p ^ key(r).
  auto stage_a = [&](int buf, int t) {
#pragma unroll
    for (int i = 0; i < 8; ++i) {
      const int r   = w * 8 + i;
      const int key = ((r & 15) << 1) | ((r >> 3) & 1);
      const float* src =
          adj + (size_t)(row0 + r) * NROW + t * 256 + ((lane ^ key) << 2);
      __builtin_amdgcn_global_load_lds(
          (const __attribute__((address_space(1))) void*)src,
          (__attribute__((address_space(3))) void*)(&LdsA[buf][r * 1024]),
          16, 0, 2 /* NT: don't cache the zero-reuse adj stream */);
    }
  };

  // --- B fragments for one K-step: 8 kk x 4 ci, register-resident.
  const __bf16* __restrict__ Bpw = Bp + ((size_t)(wc * 4) * 64 + lane) * 8;
  v8bf b[8][4];
  auto load_b = [&](int t) {
#pragma unroll
    for (int kk = 0; kk < 8; ++kk)
#pragma unroll
      for (int ci = 0; ci < 4; ++ci)
        b[kk][ci] =
            *(const v8bf*)(Bpw + ((size_t)((t * 8 + kk) * 16 + ci)) * 512);
  };

  auto compute = [&](int buf) {
    const char* ab = &LdsA[buf][0];
#pragma unroll
    for (int kk = 0; kk < 8; ++kk) {
      v8bf af[2];
#pragma unroll
      for (int rt = 0; rt < 2; ++rt) {
        const int r   = wr * 32 + rt * 16 + llo;
        const int key = ((r & 15) << 1) | ((r >> 3) & 1);
        const char* base = ab + r * 1024;
        v4f u0 = *(const v4f*)(base + (((kk * 8 + lhi * 2    ) ^ key) << 4));
        v4f u1 = *(const v4f*)(base + (((kk * 8 + lhi * 2 + 1) ^ key) << 4));
        af[rt] = cvt_bf8(u0, u1);
      }
#pragma unroll
      for (int ci = 0; ci < 4; ++ci)
#pragma unroll
        for (int rt = 0; rt < 2; ++rt)
          acc[rt][ci] = __builtin_amdgcn_mfma_f32_16x16x32_bf16(
              af[rt], b[kk][ci], acc[rt][ci], 0, 0, 0);
    }
  };

  stage_a(0, 0);

#pragma unroll 1
  for (int t = 0; t < NSTEP; ++t) {
    asm volatile("s_waitcnt vmcnt(0)" ::: "memory");  // A(t) landed (only A outstanding)
    __builtin_amdgcn_s_barrier();                     // A(t) visible to all waves
    load_b(t);                                        // B first in FIFO
    __builtin_amdgcn_sched_barrier(0);
    if (t + 1 < NSTEP) stage_a((t + 1) & 1, t + 1);   // then next A-tile
    __builtin_amdgcn_sched_barrier(0);
    compute(t & 1);                                   // compiler-counted B-waits
  }

  // epilogue: bias + prelu, direct store
  const float slope = prelu_a[0];
  float* __restrict__ outp = out + (size_t)z * M_ELEM;
#pragma unroll
  for (int ci = 0; ci < 4; ++ci) {
    const int o  = wc * 64 + ci * 16 + llo;
    const float bs = bias[o];
#pragma unroll
    for (int rt = 0; rt < 2; ++rt) {
      const int m = row0 + wr * 32 + rt * 16 + lhi * 4;
#pragma unroll
      for (int r = 0; r < 4; ++r) {
        float v = acc[rt][ci][r] + bs;
        outp[(size_t)(m + r) * OUTF + o] = v >= 0.f ? v : slope * v;
      }
    }
  }
}

extern "C" void kernel_launch(void* const* d_in, const int* in_sizes, int n_in,
                              void* d_out, int out_size, void* d_ws, size_t ws_size,
                              hipStream_t stream) {
  const float* feat = (const float*)d_in[0];
  const float* adj  = (const float*)d_in[1];
  const float* aug  = (const float*)d_in[2];
  const float* W    = (const float*)d_in[3];
  const float* bias = (const float*)d_in[4];
  const float* pa   = (const float*)d_in[5];
  float* out = (float*)d_out;
  __bf16* Bp = (__bf16*)d_ws;                    // 4 MB packed seq_fts

  seq_fts_kernel<<<dim3(NROW / 64), 256, 0, stream>>>(feat, W, Bp);
  gcn_agg_kernel<<<dim3(NROW / 64, 2), 512, 0, stream>>>(
      adj, aug, Bp, bias, pa, out);
}

// Round 10
// 207.399 us; speedup vs baseline: 1.7169x; 1.0026x over previous
//
#include <hip/hip_runtime.h>

#define NROW 8192
#define INF  512
#define OUTF 256
#define M_ELEM (NROW * OUTF)   // 2,097,152 f32 per output matrix
#define NSTEP 32               // K-steps of 256

typedef __bf16 v8bf __attribute__((ext_vector_type(8)));
typedef __bf16 v4bf __attribute__((ext_vector_type(4)));
typedef float  v4f  __attribute__((ext_vector_type(4)));

__device__ __forceinline__ v8bf cvt_bf8(v4f u0, v4f u1) {
  v8bf v;
  v[0]=(__bf16)u0[0]; v[1]=(__bf16)u0[1]; v[2]=(__bf16)u0[2]; v[3]=(__bf16)u0[3];
  v[4]=(__bf16)u1[0]; v[5]=(__bf16)u1[1]; v[6]=(__bf16)u1[2]; v[7]=(__bf16)u1[3];
  return v;
}

// ---------------------------------------------------------------------------
// Kernel A: seq = feat @ W^T, bf16 MFMA, output in B-fragment-packed layout:
//   elem(m,o) -> (((m>>5)*16 + (o>>4))*64 + ((m>>3)&3)*16 + (o&15))*8 + (m&7)
// ---------------------------------------------------------------------------
__global__ __launch_bounds__(256) void seq_fts_kernel(
    const float* __restrict__ feat, const float* __restrict__ W,
    __bf16* __restrict__ Bp) {
  const int tid  = threadIdx.x;
  const int lane = tid & 63, w = tid >> 6;
  const int llo  = lane & 15, lhi = lane >> 4;
  const int row0 = blockIdx.x * 64;
  const int col0 = w * 64;

  v4f acc[4][4] = {};
#pragma unroll 1
  for (int kb = 0; kb < INF / 32; ++kb) {
    const int kofs = kb * 32 + lhi * 8;
    v8bf a[4], b[4];
#pragma unroll
    for (int i = 0; i < 4; ++i) {
      const float* p = feat + (size_t)(row0 + i * 16 + llo) * INF + kofs;
      a[i] = cvt_bf8(*(const v4f*)p, *(const v4f*)(p + 4));
    }
#pragma unroll
    for (int i = 0; i < 4; ++i) {
      const float* p = W + (size_t)(col0 + i * 16 + llo) * INF + kofs;
      b[i] = cvt_bf8(*(const v4f*)p, *(const v4f*)(p + 4));
    }
#pragma unroll
    for (int ri = 0; ri < 4; ++ri)
#pragma unroll
      for (int ci = 0; ci < 4; ++ci)
        acc[ri][ci] = __builtin_amdgcn_mfma_f32_16x16x32_bf16(
            a[ri], b[ci], acc[ri][ci], 0, 0, 0);
  }
#pragma unroll
  for (int ri = 0; ri < 4; ++ri)
#pragma unroll
    for (int ci = 0; ci < 4; ++ci) {
      const int mf = row0 + ri * 16 + lhi * 4;
      const int o  = col0 + ci * 16 + llo;
      size_t e = (((size_t)(mf >> 5) * 16 + (o >> 4)) * 64 +
                  ((mf >> 3) & 3) * 16 + (o & 15)) * 8 + (mf & 7);
      v4bf v;
      v[0] = (__bf16)acc[ri][ci][0]; v[1] = (__bf16)acc[ri][ci][1];
      v[2] = (__bf16)acc[ri][ci][2]; v[3] = (__bf16)acc[ri][ci][3];
      *(v4bf*)(Bp + e) = v;
    }
}

// ---------------------------------------------------------------------------
// Kernel B: out = prelu(adj @ seq + bias).  R9 structure with the VGPR fix:
//  - __launch_bounds__(512,1): R9's (512,2) capped VGPR at 128, forcing the
//    compiler to break the 128-VGPR b-array into serially-waited chunks
//    (exposed L2 latency ~8x/step). Now the full b-set fits in registers.
//  - b split into two [4][4] half-sets, BOTH issued upfront in FIFO order
//    bh0, bh1, A(t+1): compute(h0) waits bh0 -> bh1 & A stay in flight;
//    compute(h1) waits bh1 -> A(t+1) stays in flight.
//  - A: 1 KB contiguous per row via global_load_lds (NT), XOR-swizzled via
//    pre-swizzled source slots; one vmcnt(0)+barrier per step (A(t) only).
// ---------------------------------------------------------------------------
__global__ __launch_bounds__(512, 1) void gcn_agg_kernel(
    const float* __restrict__ adjA, const float* __restrict__ adjB,
    const __bf16* __restrict__ Bp, const float* __restrict__ bias,
    const float* __restrict__ prelu_a, float* __restrict__ out) {
  const int tid  = threadIdx.x;
  const int lane = tid & 63, w = tid >> 6;
  const int llo  = lane & 15, lhi = lane >> 4;
  const int wr   = w >> 2, wc = w & 3;     // 2 row-groups x 4 col-groups
  const int row0 = blockIdx.x * 64;
  const int z    = blockIdx.y;
  const float* __restrict__ adj = z ? adjB : adjA;

  __shared__ __align__(16) char LdsA[2][65536];   // 2 x (64 rows x 1 KB)

  v4f acc[2][4] = {};

  // --- A staging: 8 instr/wave, each = one row's 1 KB contiguous chunk.
  // LDS row r slot p (16B units) holds source slot p ^ key(r).
  auto stage_a = [&](int buf, int t) {
#pragma unroll
    for (int i = 0; i < 8; ++i) {
      const int r   = w * 8 + i;
      const int key = ((r & 15) << 1) | ((r >> 3) & 1);
      const float* src =
          adj + (size_t)(row0 + r) * NROW + t * 256 + ((lane ^ key) << 2);
      __builtin_amdgcn_global_load_lds(
          (const __attribute__((address_space(1))) void*)src,
          (__attribute__((address_space(3))) void*)(&LdsA[buf][r * 1024]),
          16, 0, 2 /* NT: don't cache the zero-reuse adj stream */);
    }
  };

  // --- B fragments, half-step granularity: [4 kk][4 ci] = 64 VGPR per half.
  const __bf16* __restrict__ Bpw = Bp + ((size_t)(wc * 4) * 64 + lane) * 8;
  auto load_bh = [&](int t, int h, v8bf (&b)[4][4]) {
#pragma unroll
    for (int kk = 0; kk < 4; ++kk)
#pragma unroll
      for (int ci = 0; ci < 4; ++ci)
        b[kk][ci] = *(const v8bf*)(
            Bpw + ((size_t)((t * 8 + h * 4 + kk) * 16 + ci)) * 512);
  };

  auto compute_h = [&](int buf, int h, v8bf (&b)[4][4]) {
    const char* ab = &LdsA[buf][0];
#pragma unroll
    for (int kk = 0; kk < 4; ++kk) {
      const int kg = h * 4 + kk;
      v8bf af[2];
#pragma unroll
      for (int rt = 0; rt < 2; ++rt) {
        const int r   = wr * 32 + rt * 16 + llo;
        const int key = ((r & 15) << 1) | ((r >> 3) & 1);
        const char* base = ab + r * 1024;
        v4f u0 = *(const v4f*)(base + (((kg * 8 + lhi * 2    ) ^ key) << 4));
        v4f u1 = *(const v4f*)(base + (((kg * 8 + lhi * 2 + 1) ^ key) << 4));
        af[rt] = cvt_bf8(u0, u1);
      }
#pragma unroll
      for (int ci = 0; ci < 4; ++ci)
#pragma unroll
        for (int rt = 0; rt < 2; ++rt)
          acc[rt][ci] = __builtin_amdgcn_mfma_f32_16x16x32_bf16(
              af[rt], b[kk][ci], acc[rt][ci], 0, 0, 0);
    }
  };

  stage_a(0, 0);

  v8bf bh0[4][4], bh1[4][4];
#pragma unroll 1
  for (int t = 0; t < NSTEP; ++t) {
    asm volatile("s_waitcnt vmcnt(0)" ::: "memory");  // A(t) landed (only A outstanding)
    __builtin_amdgcn_s_barrier();                     // A(t) visible to all waves
    load_bh(t, 0, bh0);                               // FIFO: bh0 (oldest)
    __builtin_amdgcn_sched_barrier(0);
    load_bh(t, 1, bh1);                               // then bh1
    __builtin_amdgcn_sched_barrier(0);
    if (t + 1 < NSTEP) stage_a((t + 1) & 1, t + 1);   // then next A-tile (newest)
    __builtin_amdgcn_sched_barrier(0);
    compute_h(t & 1, 0, bh0);   // waits bh0 -> bh1 + A(t+1) stay in flight
    compute_h(t & 1, 1, bh1);   // waits bh1 -> A(t+1) stays in flight
  }

  // epilogue: bias + prelu, direct store
  const float slope = prelu_a[0];
  float* __restrict__ outp = out + (size_t)z * M_ELEM;
#pragma unroll
  for (int ci = 0; ci < 4; ++ci) {
    const int o  = wc * 64 + ci * 16 + llo;
    const float bs = bias[o];
#pragma unroll
    for (int rt = 0; rt < 2; ++rt) {
      const int m = row0 + wr * 32 + rt * 16 + lhi * 4;
#pragma unroll
      for (int r = 0; r < 4; ++r) {
        float v = acc[rt][ci][r] + bs;
        outp[(size_t)(m + r) * OUTF + o] = v >= 0.f ? v : slope * v;
      }
    }
  }
}

extern "C" void kernel_launch(void* const* d_in, const int* in_sizes, int n_in,
                              void* d_out, int out_size, void* d_ws, size_t ws_size,
                              hipStream_t stream) {
  const float* feat = (const float*)d_in[0];
  const float* adj  = (const float*)d_in[1];
  const float* aug  = (const float*)d_in[2];
  const float* W    = (const float*)d_in[3];
  const float* bias = (const float*)d_in[4];
  const float* pa   = (const float*)d_in[5];
  float* out = (float*)d_out;
  __bf16* Bp = (__bf16*)d_ws;                    // 4 MB packed seq_fts

  seq_fts_kernel<<<dim3(NROW / 64), 256, 0, stream>>>(feat, W, Bp);
  gcn_agg_kernel<<<dim3(NROW / 64, 2), 512, 0, stream>>>(
      adj, aug, Bp, bias, pa, out);
}